// Round 7
// baseline (172.495 us; speedup 1.0000x reference)
//
#include <hip/hip_runtime.h>

#define B_ 8
#define C_ 256
#define N_ 2048
#define D_ 256
#define KKEEP 1843      // round(2048 * 0.9)
#define LEAKY 0.01f
#define EPS 1e-5f
#define L2E 1.4426950408889634f

using short8  = __attribute__((ext_vector_type(8))) short;
using ushort8 = __attribute__((ext_vector_type(8))) unsigned short;
using ushort4v = __attribute__((ext_vector_type(4))) unsigned short;
using f32x4   = __attribute__((ext_vector_type(4))) float;

__device__ inline unsigned short f2bf(float x) {          // RNE f32->bf16
  unsigned u = __float_as_uint(x);
  u += 0x7fffu + ((u >> 16) & 1u);
  return (unsigned short)(u >> 16);
}
__device__ inline float bf2f(unsigned short u) { return __uint_as_float(((unsigned)u) << 16); }

// ---------- transpose + cast: src (rows x cols) fp32 -> dst (cols x rows) bf16
__global__ __launch_bounds__(256) void k_transpose_cast(const float* __restrict__ src,
                                                        unsigned short* __restrict__ dst,
                                                        int rows, int cols,
                                                        size_t srcBatch, size_t dstBatch) {
  __shared__ float tile[32][33];
  int b = blockIdx.z;
  src += (size_t)b * srcBatch;
  dst += (size_t)b * dstBatch;
  int i0 = blockIdx.y * 32;   // src row (c)
  int j0 = blockIdx.x * 32;   // src col (n)
  int t = threadIdx.x;
  int tc = t & 31, tr = t >> 5;
#pragma unroll
  for (int k = 0; k < 4; ++k)
    tile[tr + k * 8][tc] = src[(size_t)(i0 + tr + k * 8) * cols + j0 + tc];
  __syncthreads();
  int r2 = t >> 3, q = t & 7;                 // write row j0+r2, 4 consecutive c
  ushort4v v;
#pragma unroll
  for (int l = 0; l < 4; ++l) v[l] = f2bf(tile[q * 4 + l][r2]);
  *(ushort4v*)&dst[(size_t)(j0 + r2) * rows + i0 + q * 4] = v;
}

// ---------- NT MFMA GEMM (support + gram): C[i][j] = sum_k A[i][k] * Bt[j][k]
template<int K_, int BN, bool SWZ>
__global__ __launch_bounds__(256) void k_gemm(const short* __restrict__ A,
                                              const short* __restrict__ Bt,
                                              unsigned short* __restrict__ Cout,
                                              size_t aStride, size_t bStride, size_t cStride,
                                              int ldc, int nx) {
  constexpr int FI = (BN == 128) ? 4 : 2;
  __shared__ short As[128][44];   // 88B row stride
  __shared__ short Bs[BN][44];
  int b, bxi, byi;
  if constexpr (SWZ) {
    int lin = blockIdx.x;
    b = lin & 7;                 // XCD id == batch
    int rest = lin >> 3;
    bxi = rest % nx;
    byi = rest / nx;
  } else {
    b = blockIdx.z; bxi = blockIdx.x; byi = blockIdx.y;
  }
  A += (size_t)b * aStride;
  Bt += (size_t)b * bStride;
  int bi = byi * 128;
  int bj = bxi * BN;
  int t = threadIdx.x;
  int lane = t & 63, wid = t >> 6;
  int wr, wc;
  if constexpr (BN == 128) { wr = (wid >> 1) * 64; wc = (wid & 1) * 64; }
  else                     { wr = wid * 32;        wc = 0; }

  int r0 = t >> 2, k0 = (t & 3) * 8;
  int r1 = r0 + 64;
  const short* aP0 = A + (size_t)(bi + r0) * K_ + k0;
  const short* aP1 = A + (size_t)(bi + r1) * K_ + k0;
  const short* bP0 = Bt + (size_t)(bj + r0) * K_ + k0;
  const short* bP1 = Bt + (size_t)(bj + (BN == 128 ? r1 : r0)) * K_ + k0;

  short8 a0 = *(const short8*)aP0;
  short8 a1 = *(const short8*)aP1;
  short8 b0 = *(const short8*)bP0;
  short8 b1;
  if constexpr (BN == 128) b1 = *(const short8*)bP1;

  f32x4 acc[FI][4];
  f32x4 z = {0.f, 0.f, 0.f, 0.f};
#pragma unroll
  for (int i = 0; i < FI; ++i)
#pragma unroll
    for (int j = 0; j < 4; ++j) acc[i][j] = z;

  int fr = lane & 15;
  int ks = (lane >> 4) * 8;

  for (int c0 = 0; c0 < K_; c0 += 32) {
    __syncthreads();
    *(short8*)&As[r0][k0] = a0;
    *(short8*)&As[r1][k0] = a1;
    *(short8*)&Bs[r0][k0] = b0;
    if constexpr (BN == 128) *(short8*)&Bs[r1][k0] = b1;
    __syncthreads();
    if (c0 + 32 < K_) {
      a0 = *(const short8*)(aP0 + c0 + 32);
      a1 = *(const short8*)(aP1 + c0 + 32);
      b0 = *(const short8*)(bP0 + c0 + 32);
      if constexpr (BN == 128) b1 = *(const short8*)(bP1 + c0 + 32);
    }
    short8 af[FI], bf[4];
#pragma unroll
    for (int f = 0; f < FI; ++f) af[f] = *(const short8*)&As[wr + f * 16 + fr][ks];
#pragma unroll
    for (int f = 0; f < 4; ++f)  bf[f] = *(const short8*)&Bs[wc + f * 16 + fr][ks];
#pragma unroll
    for (int fi = 0; fi < FI; ++fi)
#pragma unroll
      for (int fj = 0; fj < 4; ++fj)
        acc[fi][fj] = __builtin_amdgcn_mfma_f32_16x16x32_bf16(af[fi], bf[fj], acc[fi][fj], 0, 0, 0);
  }

  int orow = (lane >> 4) * 4;
  int ocol = lane & 15;
#pragma unroll
  for (int fi = 0; fi < FI; ++fi)
#pragma unroll
    for (int fj = 0; fj < 4; ++fj)
#pragma unroll
      for (int r = 0; r < 4; ++r) {
        size_t idx = (size_t)b * cStride +
                     (size_t)(bi + wr + fi * 16 + orow + r) * ldc +
                     (size_t)(bj + wc + fj * 16 + ocol);
        Cout[idx] = f2bf(acc[fi][fj][r]);
      }
}

// ---------- per-row stats: softmax params + topk threshold (raw-score space)
// one WAVE per row; writes {nm = -max*L2E, inv = 1/sumexp, thr_f32, 0} per row.
__global__ __launch_bounds__(256) void k_rowstats(const unsigned short* __restrict__ S,
                                                  float4* __restrict__ rowp) {
  int t = threadIdx.x;
  int lane = t & 63, wv = t >> 6;
  size_t row = (size_t)blockIdx.x * 4 + wv;
  const unsigned short* sr = S + row * N_;

  float sc[32];
#pragma unroll
  for (int i = 0; i < 4; ++i) {
    ushort8 raw = *(const ushort8*)(sr + ((size_t)(i * 64 + lane)) * 8);
#pragma unroll
    for (int j = 0; j < 8; ++j) sc[i * 8 + j] = bf2f(raw[j]);
  }

  float lm = sc[0];
#pragma unroll
  for (int j = 1; j < 32; ++j) lm = fmaxf(lm, sc[j]);
#pragma unroll
  for (int m = 1; m <= 16; m <<= 1) lm = fmaxf(lm, __shfl_xor(lm, m));
  lm = fmaxf(__shfl(lm, 0), __shfl(lm, 32));
  float nm = -lm * L2E;

  // e = exp2(s*L2E + nm); keys = bf16(e), transpose-paired (j, j+16)
  float ls = 0.f;
  unsigned kp[16];
#pragma unroll
  for (int q = 0; q < 16; ++q) {
    float ea = exp2f(fmaf(sc[q], L2E, nm));
    float eb = exp2f(fmaf(sc[q + 16], L2E, nm));
    ls += ea + eb;
    kp[q] = (unsigned)f2bf(ea) | ((unsigned)f2bf(eb) << 16);
  }
#pragma unroll
  for (int m = 1; m <= 16; m <<= 1) ls += __shfl_xor(ls, m);
  ls = __shfl(ls, 0) + __shfl(ls, 32);

  // bit-plane transpose: tp[b] bit j == bit b of key[j]
  unsigned tp[16];
#pragma unroll
  for (int q = 0; q < 16; ++q) tp[q] = kp[q];
#pragma unroll
  for (int sI = 0; sI < 4; ++sI) {
    const int s = 8 >> sI;
    const unsigned msk = (s == 8) ? 0x00FF00FFu : (s == 4) ? 0x0F0F0F0Fu
                       : (s == 2) ? 0x33333333u : 0x55555555u;
#pragma unroll
    for (int k = 0; k < 16; ++k) {
      if ((k & s) == 0) {
        unsigned tt = ((tp[k] >> s) ^ tp[k + s]) & msk;
        tp[k + s] ^= tt;
        tp[k]     ^= tt << s;
      }
    }
  }

  // radix-4 select over bits 13..0 (keys <= 0x3F80)
  unsigned alive = 0xFFFFFFFFu, prefix = 0u;
  int need = KKEEP;
#pragma unroll
  for (int b = 12; b >= 0; b -= 2) {
    unsigned p1 = tp[b + 1], p0 = tp[b];
    unsigned hi = alive & p1;
    unsigned m3 = hi & p0, m2 = hi & ~p0, m1v = (alive & ~p1) & p0;
    unsigned packed = (unsigned)__popc(m3) | ((unsigned)__popc(m2) << 11) |
                      ((unsigned)__popc(m1v) << 22);
#pragma unroll
    for (int m = 1; m <= 16; m <<= 1) packed += __shfl_xor(packed, m);
    unsigned v0 = __shfl(packed, 0), v32 = __shfl(packed, 32);
    int C3 = (int)((v0 & 0x7FFu) + (v32 & 0x7FFu));
    int C2 = (int)(((v0 >> 11) & 0x7FFu) + ((v32 >> 11) & 0x7FFu));
    int C1 = (int)(((v0 >> 22) & 0x7FFu) + ((v32 >> 22) & 0x7FFu));
    int cum2 = C3 + C2, cum1 = cum2 + C1;
    if (C3 >= need)        { alive = m3;  prefix |= 3u << b; }
    else if (cum2 >= need) { alive = m2;  prefix |= 2u << b; need -= C3; }
    else if (cum1 >= need) { alive = m1v; prefix |= 1u << b; need -= cum2; }
    else                   { alive ^= (m3 | m2 | m1v);       need -= cum1; }
  }

  // raw-score threshold: thr = min{ s_j : key_j >= prefix }.
  // key monotone nondecreasing in s  =>  {key >= prefix} == {s >= thr} exactly.
  float thr = 1e30f;
#pragma unroll
  for (int j = 0; j < 32; ++j) {
    unsigned key = (kp[j & 15] >> ((j >> 4) * 16)) & 0xFFFFu;
    if (key >= prefix) thr = fminf(thr, sc[j]);
  }
#pragma unroll
  for (int m = 1; m <= 16; m <<= 1) thr = fminf(thr, __shfl_xor(thr, m));
  thr = fminf(__shfl(thr, 0), __shfl(thr, 32));

  if (lane == 0) rowp[row] = make_float4(nm, 1.0f / ls, thr, 0.f);
}

// masked softmax prob from raw bf16 scores (must match k_rowstats formulas)
__device__ inline short8 cvt_mask(short8 raw, float nm, float iv, float thr) {
  short8 o;
#pragma unroll
  for (int j = 0; j < 8; ++j) {
    float s = bf2f((unsigned short)raw[j]);
    float e = exp2f(fmaf(s, L2E, nm));
    float p = (s >= thr) ? e * iv : 0.f;
    o[j] = (short)f2bf(p);
  }
  return o;
}

// ---------- PV GEMM: pre(n,d) = P . supT^T with on-the-fly softmax mask,
// leaky-relu epilogue, bf16 output, fused BN partial stats. 128x64 tile, FI=2.
__global__ __launch_bounds__(256) void k_pv(const short* __restrict__ A,   // raw S bf16
                                            const short* __restrict__ Bt,  // supT
                                            const float4* __restrict__ rowp,
                                            unsigned short* __restrict__ pre,
                                            float* __restrict__ ps, float* __restrict__ pss) {
  __shared__ short As[128][44];
  __shared__ short Bs[64][44];
  int lin = blockIdx.x;
  int b = lin & 7;                 // batch -> XCD
  int rest = lin >> 3;
  int bxi = rest & 3;              // nx = 4
  int byi = rest >> 2;
  const short* Ab = A + (size_t)b * N_ * N_;
  const short* Bb = Bt + (size_t)b * D_ * N_;
  int bi = byi * 128, bj = bxi * 64;
  int t = threadIdx.x, lane = t & 63, wid = t >> 6;
  int wr = wid * 32;

  int r0 = t >> 2, k0 = (t & 3) * 8;
  int r1 = r0 + 64;
  const short* aP0 = Ab + (size_t)(bi + r0) * N_ + k0;
  const short* aP1 = Ab + (size_t)(bi + r1) * N_ + k0;
  const short* bP0 = Bb + (size_t)(bj + r0) * N_ + k0;

  float4 rp0 = rowp[(size_t)b * N_ + bi + r0];
  float4 rp1 = rowp[(size_t)b * N_ + bi + r1];

  short8 a0 = *(const short8*)aP0;
  short8 a1 = *(const short8*)aP1;
  short8 b0 = *(const short8*)bP0;

  f32x4 acc[2][4];
  f32x4 z = {0.f, 0.f, 0.f, 0.f};
#pragma unroll
  for (int i = 0; i < 2; ++i)
#pragma unroll
    for (int j = 0; j < 4; ++j) acc[i][j] = z;

  int fr = lane & 15;
  int ks = (lane >> 4) * 8;

  for (int c0 = 0; c0 < N_; c0 += 32) {
    __syncthreads();
    *(short8*)&As[r0][k0] = cvt_mask(a0, rp0.x, rp0.y, rp0.z);
    *(short8*)&As[r1][k0] = cvt_mask(a1, rp1.x, rp1.y, rp1.z);
    *(short8*)&Bs[r0][k0] = b0;
    __syncthreads();
    if (c0 + 32 < N_) {
      a0 = *(const short8*)(aP0 + c0 + 32);
      a1 = *(const short8*)(aP1 + c0 + 32);
      b0 = *(const short8*)(bP0 + c0 + 32);
    }
    short8 af[2], bf[4];
#pragma unroll
    for (int f = 0; f < 2; ++f) af[f] = *(const short8*)&As[wr + f * 16 + fr][ks];
#pragma unroll
    for (int f = 0; f < 4; ++f) bf[f] = *(const short8*)&Bs[f * 16 + fr][ks];
#pragma unroll
    for (int fi = 0; fi < 2; ++fi)
#pragma unroll
      for (int fj = 0; fj < 4; ++fj)
        acc[fi][fj] = __builtin_amdgcn_mfma_f32_16x16x32_bf16(af[fi], bf[fj], acc[fi][fj], 0, 0, 0);
  }

  // epilogue: leaky + bf16 store + per-column (channel) partial sums
  int orow = (lane >> 4) * 4;
  int ocol = lane & 15;
  float s4[4] = {0.f, 0.f, 0.f, 0.f}, ss4[4] = {0.f, 0.f, 0.f, 0.f};
#pragma unroll
  for (int fi = 0; fi < 2; ++fi)
#pragma unroll
    for (int r = 0; r < 4; ++r) {
      int rowg = bi + wr + fi * 16 + orow + r;
      size_t base = ((size_t)b * N_ + rowg) * D_ + bj;
#pragma unroll
      for (int fj = 0; fj < 4; ++fj) {
        float v = acc[fi][fj][r];
        v = (v >= 0.f) ? v : LEAKY * v;
        pre[base + fj * 16 + ocol] = f2bf(v);
        s4[fj] += v;
        ss4[fj] = fmaf(v, v, ss4[fj]);
      }
    }
#pragma unroll
  for (int fj = 0; fj < 4; ++fj) {
    s4[fj] += __shfl_xor(s4[fj], 16);  s4[fj] += __shfl_xor(s4[fj], 32);
    ss4[fj] += __shfl_xor(ss4[fj], 16); ss4[fj] += __shfl_xor(ss4[fj], 32);
  }
  __syncthreads();                        // done with As as bf16 tile
  float* sred = (float*)As;               // reuse LDS: 512 floats
  if (lane < 16) {
#pragma unroll
    for (int fj = 0; fj < 4; ++fj) {
      sred[(wid * 4 + fj) * 16 + lane] = s4[fj];
      sred[256 + (wid * 4 + fj) * 16 + lane] = ss4[fj];
    }
  }
  __syncthreads();
  if (t < 64) {
    float s = 0.f, ss = 0.f;
#pragma unroll
    for (int w4 = 0; w4 < 4; ++w4) {
      s  += sred[(w4 * 4 + (t >> 4)) * 16 + (t & 15)];
      ss += sred[256 + (w4 * 4 + (t >> 4)) * 16 + (t & 15)];
    }
    ps[(size_t)lin * 64 + t] = s;
    pss[(size_t)lin * 64 + t] = ss;
  }
}

// ---------- BN finalize: reduce 512-block partials -> scale/shift per channel
__global__ void k_final(const float* __restrict__ ps, const float* __restrict__ pss,
                        const float* __restrict__ bnw, const float* __restrict__ bnb,
                        float* __restrict__ scale, float* __restrict__ shift) {
  int t = threadIdx.x;  // 256 channels
  int bxi = t >> 6, col = t & 63;
  float s = 0.f, ss = 0.f;
  for (int byi = 0; byi < 16; ++byi)
    for (int bb = 0; bb < 8; ++bb) {
      int lin = (byi * 4 + bxi) * 8 + bb;
      s += ps[(size_t)lin * 64 + col];
      ss += pss[(size_t)lin * 64 + col];
    }
  const float invN = 1.0f / (B_ * N_);
  float mean = s * invN;
  float var = fmaf(-mean, mean, ss * invN);
  float istd = rsqrtf(var + EPS);
  float sc = istd * bnw[t];
  scale[t] = sc;
  shift[t] = fmaf(-mean, sc, bnb[t]);
}

// ---------- normalize + transpose (b,n,d) bf16 -> (b,d,n) f32
__global__ __launch_bounds__(256) void k_out(const unsigned short* __restrict__ pre,
                                             const float* __restrict__ scale,
                                             const float* __restrict__ shift,
                                             float* __restrict__ out) {
  __shared__ float tile[32][33];
  int blk = blockIdx.x;
  int d0 = (blk % (D_ / 32)) * 32;
  int n0 = ((blk / (D_ / 32)) % (N_ / 32)) * 32;
  int b = blk / ((D_ / 32) * (N_ / 32));
  int tc = threadIdx.x & 31;
  int tr = threadIdx.x >> 5;
  const unsigned short* pb = pre + ((size_t)b * N_ + n0) * D_ + d0;
#pragma unroll
  for (int i = 0; i < 4; ++i) {
    int r = tr + i * 8;
    tile[r][tc] = bf2f(pb[(size_t)r * D_ + tc]);
  }
  __syncthreads();
  float* ob = out + ((size_t)b * D_ + d0) * N_ + n0;
#pragma unroll
  for (int i = 0; i < 4; ++i) {
    int r = tr + i * 8;
    float vv = tile[tc][r];
    ob[(size_t)r * N_ + tc] = fmaf(vv, scale[d0 + r], shift[d0 + r]);
  }
}

extern "C" void kernel_launch(void* const* d_in, const int* in_sizes, int n_in,
                              void* d_out, int out_size, void* d_ws, size_t ws_size,
                              hipStream_t stream) {
  const float* x = (const float*)d_in[0];
  const float* W = (const float*)d_in[1];
  const float* bnw = (const float*)d_in[2];
  const float* bnb = (const float*)d_in[3];
  float* out = (float*)d_out;

  char* w = (char*)d_ws;
  short* xt = (short*)w;            w += (size_t)B_ * N_ * C_ * 2;     // (b,n,c) bf16
  short* wt = (short*)w;            w += (size_t)D_ * C_ * 2;          // (d,c) bf16
  short* supT = (short*)w;          w += (size_t)B_ * D_ * N_ * 2;     // (b,d,m) bf16
  short* S = (short*)w;             w += (size_t)B_ * N_ * N_ * 2;     // (b,n,m) raw scores bf16
  unsigned short* pre = (unsigned short*)w; w += (size_t)B_ * N_ * D_ * 2; // (b,n,d) bf16
  float4* rowp = (float4*)w;        w += (size_t)B_ * N_ * 16;         // per-row params
  float* ps = (float*)w;            w += (size_t)512 * 64 * 4;         // stat partials
  float* pss = (float*)w;           w += (size_t)512 * 64 * 4;
  float* scale = (float*)w;         w += D_ * 4;
  float* shift = (float*)w;         w += D_ * 4;

  // 1. layout prep
  k_transpose_cast<<<dim3(N_ / 32, C_ / 32, B_), 256, 0, stream>>>(
      x, (unsigned short*)xt, C_, N_, (size_t)C_ * N_, (size_t)N_ * C_);
  k_transpose_cast<<<dim3(D_ / 32, C_ / 32, 1), 256, 0, stream>>>(
      W, (unsigned short*)wt, C_, D_, 0, 0);

  // 2. supT(d,m) = wt . xt^T
  k_gemm<C_, 64, false><<<dim3(N_ / 64, 2, B_), 256, 0, stream>>>(
      wt, xt, (unsigned short*)supT, 0, (size_t)N_ * C_, (size_t)D_ * N_, N_, 0);

  // 3. S(n,m) = xt . xt^T  — batch->XCD pinned
  k_gemm<C_, 128, true><<<dim3(16 * 16 * B_, 1, 1), 256, 0, stream>>>(
      xt, xt, (unsigned short*)S, (size_t)N_ * C_, (size_t)N_ * C_, (size_t)N_ * N_, N_, 16);

  // 4. per-row softmax params + topk threshold (reads raw S once)
  k_rowstats<<<B_ * N_ / 4, 256, 0, stream>>>((unsigned short*)S, rowp);

  // 5. PV with fused mask+softmax staging, leaky, bf16 out, fused BN partials
  k_pv<<<dim3(4 * 16 * B_, 1, 1), 256, 0, stream>>>(
      S, supT, rowp, pre, ps, pss);

  // 6. finalize BN + output
  k_final<<<1, 256, 0, stream>>>(ps, pss, bnw, bnb, scale, shift);
  k_out<<<B_ * (N_ / 32) * (D_ / 32), 256, 0, stream>>>(pre, scale, shift, out);
}

// Round 8
// 120.708 us; speedup vs baseline: 1.4290x; 1.4290x over previous
//
#include <hip/hip_runtime.h>

#define B_ 8
#define C_ 256
#define N_ 2048
#define D_ 256
#define KKEEP 1843      // round(2048 * 0.9)
#define LEAKY 0.01f
#define EPS 1e-5f

using short8  = __attribute__((ext_vector_type(8))) short;
using ushort8 = __attribute__((ext_vector_type(8))) unsigned short;
using ushort4v = __attribute__((ext_vector_type(4))) unsigned short;
using f32x4   = __attribute__((ext_vector_type(4))) float;

__device__ inline unsigned short f2bf(float x) {          // RNE f32->bf16
  unsigned u = __float_as_uint(x);
  u += 0x7fffu + ((u >> 16) & 1u);
  return (unsigned short)(u >> 16);
}
__device__ inline float bf2f(unsigned short u) { return __uint_as_float(((unsigned)u) << 16); }

// ---------- transpose + cast: src (rows x cols) fp32 -> dst (cols x rows) bf16
__global__ __launch_bounds__(256) void k_transpose_cast(const float* __restrict__ src,
                                                        unsigned short* __restrict__ dst,
                                                        int rows, int cols,
                                                        size_t srcBatch, size_t dstBatch) {
  __shared__ float tile[32][33];
  int b = blockIdx.z;
  src += (size_t)b * srcBatch;
  dst += (size_t)b * dstBatch;
  int i0 = blockIdx.y * 32;   // src row (c)
  int j0 = blockIdx.x * 32;   // src col (n)
  int t = threadIdx.x;
  int tc = t & 31, tr = t >> 5;
#pragma unroll
  for (int k = 0; k < 4; ++k)
    tile[tr + k * 8][tc] = src[(size_t)(i0 + tr + k * 8) * cols + j0 + tc];
  __syncthreads();
  int r2 = t >> 3, q = t & 7;                 // write row j0+r2, 4 consecutive c
  ushort4v v;
#pragma unroll
  for (int l = 0; l < 4; ++l) v[l] = f2bf(tile[q * 4 + l][r2]);
  *(ushort4v*)&dst[(size_t)(j0 + r2) * rows + i0 + q * 4] = v;
}

// ---------- NT MFMA GEMM (support + gram): C[i][j] = sum_k A[i][k] * Bt[j][k]
template<int K_, int BN, bool SWZ>
__global__ __launch_bounds__(256) void k_gemm(const short* __restrict__ A,
                                              const short* __restrict__ Bt,
                                              unsigned short* __restrict__ Cout,
                                              size_t aStride, size_t bStride, size_t cStride,
                                              int ldc, int nx) {
  constexpr int FI = (BN == 128) ? 4 : 2;
  __shared__ short As[128][44];   // 88B row stride
  __shared__ short Bs[BN][44];
  int b, bxi, byi;
  if constexpr (SWZ) {
    int lin = blockIdx.x;
    b = lin & 7;                 // XCD id == batch
    int rest = lin >> 3;
    bxi = rest % nx;
    byi = rest / nx;
  } else {
    b = blockIdx.z; bxi = blockIdx.x; byi = blockIdx.y;
  }
  A += (size_t)b * aStride;
  Bt += (size_t)b * bStride;
  int bi = byi * 128;
  int bj = bxi * BN;
  int t = threadIdx.x;
  int lane = t & 63, wid = t >> 6;
  int wr, wc;
  if constexpr (BN == 128) { wr = (wid >> 1) * 64; wc = (wid & 1) * 64; }
  else                     { wr = wid * 32;        wc = 0; }

  int r0 = t >> 2, k0 = (t & 3) * 8;
  int r1 = r0 + 64;
  const short* aP0 = A + (size_t)(bi + r0) * K_ + k0;
  const short* aP1 = A + (size_t)(bi + r1) * K_ + k0;
  const short* bP0 = Bt + (size_t)(bj + r0) * K_ + k0;
  const short* bP1 = Bt + (size_t)(bj + (BN == 128 ? r1 : r0)) * K_ + k0;

  short8 a0 = *(const short8*)aP0;
  short8 a1 = *(const short8*)aP1;
  short8 b0 = *(const short8*)bP0;
  short8 b1;
  if constexpr (BN == 128) b1 = *(const short8*)bP1;

  f32x4 acc[FI][4];
  f32x4 z = {0.f, 0.f, 0.f, 0.f};
#pragma unroll
  for (int i = 0; i < FI; ++i)
#pragma unroll
    for (int j = 0; j < 4; ++j) acc[i][j] = z;

  int fr = lane & 15;
  int ks = (lane >> 4) * 8;

  for (int c0 = 0; c0 < K_; c0 += 32) {
    __syncthreads();
    *(short8*)&As[r0][k0] = a0;
    *(short8*)&As[r1][k0] = a1;
    *(short8*)&Bs[r0][k0] = b0;
    if constexpr (BN == 128) *(short8*)&Bs[r1][k0] = b1;
    __syncthreads();
    if (c0 + 32 < K_) {
      a0 = *(const short8*)(aP0 + c0 + 32);
      a1 = *(const short8*)(aP1 + c0 + 32);
      b0 = *(const short8*)(bP0 + c0 + 32);
      if constexpr (BN == 128) b1 = *(const short8*)(bP1 + c0 + 32);
    }
    short8 af[FI], bf[4];
#pragma unroll
    for (int f = 0; f < FI; ++f) af[f] = *(const short8*)&As[wr + f * 16 + fr][ks];
#pragma unroll
    for (int f = 0; f < 4; ++f)  bf[f] = *(const short8*)&Bs[wc + f * 16 + fr][ks];
#pragma unroll
    for (int fi = 0; fi < FI; ++fi)
#pragma unroll
      for (int fj = 0; fj < 4; ++fj)
        acc[fi][fj] = __builtin_amdgcn_mfma_f32_16x16x32_bf16(af[fi], bf[fj], acc[fi][fj], 0, 0, 0);
  }

  int orow = (lane >> 4) * 4;
  int ocol = lane & 15;
#pragma unroll
  for (int fi = 0; fi < FI; ++fi)
#pragma unroll
    for (int fj = 0; fj < 4; ++fj)
#pragma unroll
      for (int r = 0; r < 4; ++r) {
        size_t idx = (size_t)b * cStride +
                     (size_t)(bi + wr + fi * 16 + orow + r) * ldc +
                     (size_t)(bj + wc + fj * 16 + ocol);
        Cout[idx] = f2bf(acc[fi][fj][r]);
      }
}

// ---------- softmax + exact(bf16-granularity) top-k threshold + mask, one WAVE per row
__global__ __launch_bounds__(256) void k_softmax_topk(unsigned short* __restrict__ S) {
  int t = threadIdx.x;
  int lane = t & 63, wv = t >> 6;
  size_t row = (size_t)blockIdx.x * 4 + wv;
  unsigned short* sr = S + row * N_;

  float e[32];
#pragma unroll
  for (int i = 0; i < 4; ++i) {
    ushort8 raw = *(const ushort8*)(sr + ((size_t)(i * 64 + lane)) * 8);
#pragma unroll
    for (int j = 0; j < 8; ++j) e[i * 8 + j] = bf2f(raw[j]);
  }

  float lm = e[0];
#pragma unroll
  for (int j = 1; j < 32; ++j) lm = fmaxf(lm, e[j]);
#pragma unroll
  for (int m = 1; m <= 16; m <<= 1) lm = fmaxf(lm, __shfl_xor(lm, m));
  lm = fmaxf(__shfl(lm, 0), __shfl(lm, 32));

  float ls = 0.f;
#pragma unroll
  for (int j = 0; j < 32; ++j) { e[j] = __expf(e[j] - lm); ls += e[j]; }
#pragma unroll
  for (int m = 1; m <= 16; m <<= 1) ls += __shfl_xor(ls, m);
  ls = __shfl(ls, 0) + __shfl(ls, 32);
  float inv = 1.0f / ls;

  unsigned kp[16], vo[16];
#pragma unroll
  for (int q = 0; q < 16; ++q)
    kp[q] = (unsigned)f2bf(e[q]) | ((unsigned)f2bf(e[q + 16]) << 16);
#pragma unroll
  for (int q = 0; q < 16; ++q)
    vo[q] = (unsigned)f2bf(e[2 * q] * inv) | ((unsigned)f2bf(e[2 * q + 1] * inv) << 16);

  unsigned tp[16];
#pragma unroll
  for (int q = 0; q < 16; ++q) tp[q] = kp[q];
#pragma unroll
  for (int sI = 0; sI < 4; ++sI) {
    const int s = 8 >> sI;
    const unsigned msk = (s == 8) ? 0x00FF00FFu : (s == 4) ? 0x0F0F0F0Fu
                       : (s == 2) ? 0x33333333u : 0x55555555u;
#pragma unroll
    for (int k = 0; k < 16; ++k) {
      if ((k & s) == 0) {
        unsigned tt = ((tp[k] >> s) ^ tp[k + s]) & msk;
        tp[k + s] ^= tt;
        tp[k]     ^= tt << s;
      }
    }
  }

  unsigned alive = 0xFFFFFFFFu, prefix = 0u;
  int need = KKEEP;
#pragma unroll
  for (int b = 12; b >= 0; b -= 2) {
    unsigned p1 = tp[b + 1], p0 = tp[b];
    unsigned hi = alive & p1;
    unsigned m3 = hi & p0, m2 = hi & ~p0, m1v = (alive & ~p1) & p0;
    unsigned packed = (unsigned)__popc(m3) | ((unsigned)__popc(m2) << 11) |
                      ((unsigned)__popc(m1v) << 22);
#pragma unroll
    for (int m = 1; m <= 16; m <<= 1) packed += __shfl_xor(packed, m);
    unsigned v0 = __shfl(packed, 0), v32 = __shfl(packed, 32);
    int C3 = (int)((v0 & 0x7FFu) + (v32 & 0x7FFu));
    int C2 = (int)(((v0 >> 11) & 0x7FFu) + ((v32 >> 11) & 0x7FFu));
    int C1 = (int)(((v0 >> 22) & 0x7FFu) + ((v32 >> 22) & 0x7FFu));
    int cum2 = C3 + C2, cum1 = cum2 + C1;
    if (C3 >= need)        { alive = m3;  prefix |= 3u << b; }
    else if (cum2 >= need) { alive = m2;  prefix |= 2u << b; need -= C3; }
    else if (cum1 >= need) { alive = m1v; prefix |= 1u << b; need -= cum2; }
    else                   { alive ^= (m3 | m2 | m1v);       need -= cum1; }
  }

#pragma unroll
  for (int i = 0; i < 4; ++i) {
    ushort8 o;
#pragma unroll
    for (int j = 0; j < 8; ++j) {
      int idx = i * 8 + j;
      unsigned key = (kp[idx & 15] >> ((idx >> 4) * 16)) & 0xFFFFu;
      unsigned val = (vo[idx >> 1] >> ((idx & 1) * 16)) & 0xFFFFu;
      o[j] = (key >= prefix) ? (unsigned short)val : (unsigned short)0;
    }
    *(ushort8*)(sr + ((size_t)(i * 64 + lane)) * 8) = o;
  }
}

// ---------- PV GEMM: pre(n,d) = P . supT^T, BK=64, leaky + bf16 out + fused BN partials
__global__ __launch_bounds__(256) void k_pv(const short* __restrict__ A,   // masked P bf16
                                            const short* __restrict__ Bt,  // supT
                                            unsigned short* __restrict__ pre,
                                            float* __restrict__ ps, float* __restrict__ pss) {
  __shared__ short As[128][68];   // 136B row stride
  __shared__ short Bs[64][68];
  int lin = blockIdx.x;
  int b = lin & 7;                 // batch -> XCD
  int rest = lin >> 3;
  int bxi = rest & 3;              // nx = 4
  int byi = rest >> 2;
  const short* Ab = A + (size_t)b * N_ * N_;
  const short* Bb = Bt + (size_t)b * D_ * N_;
  int bi = byi * 128, bj = bxi * 64;
  int t = threadIdx.x, lane = t & 63, wid = t >> 6;
  int wr = wid * 32;

  // staging map for BK=64: row r = t>>3 (0..31), col chunk c8 = (t&7)*8
  int r = t >> 3, c8 = (t & 7) * 8;
  const short* aP0 = Ab + (size_t)(bi + r) * N_ + c8;
  const short* aP1 = Ab + (size_t)(bi + r + 32) * N_ + c8;
  const short* aP2 = Ab + (size_t)(bi + r + 64) * N_ + c8;
  const short* aP3 = Ab + (size_t)(bi + r + 96) * N_ + c8;
  const short* bP0 = Bb + (size_t)(bj + r) * N_ + c8;
  const short* bP1 = Bb + (size_t)(bj + r + 32) * N_ + c8;

  short8 a0 = *(const short8*)aP0;
  short8 a1 = *(const short8*)aP1;
  short8 a2 = *(const short8*)aP2;
  short8 a3 = *(const short8*)aP3;
  short8 b0 = *(const short8*)bP0;
  short8 b1 = *(const short8*)bP1;

  f32x4 acc[2][4];
  f32x4 z = {0.f, 0.f, 0.f, 0.f};
#pragma unroll
  for (int i = 0; i < 2; ++i)
#pragma unroll
    for (int j = 0; j < 4; ++j) acc[i][j] = z;

  int fr = lane & 15;
  int ks = (lane >> 4) * 8;

  for (int c0 = 0; c0 < N_; c0 += 64) {
    __syncthreads();
    *(short8*)&As[r][c8] = a0;
    *(short8*)&As[r + 32][c8] = a1;
    *(short8*)&As[r + 64][c8] = a2;
    *(short8*)&As[r + 96][c8] = a3;
    *(short8*)&Bs[r][c8] = b0;
    *(short8*)&Bs[r + 32][c8] = b1;
    __syncthreads();
    if (c0 + 64 < N_) {
      a0 = *(const short8*)(aP0 + c0 + 64);
      a1 = *(const short8*)(aP1 + c0 + 64);
      a2 = *(const short8*)(aP2 + c0 + 64);
      a3 = *(const short8*)(aP3 + c0 + 64);
      b0 = *(const short8*)(bP0 + c0 + 64);
      b1 = *(const short8*)(bP1 + c0 + 64);
    }
#pragma unroll
    for (int ksub = 0; ksub < 2; ++ksub) {
      short8 af[2], bf[4];
#pragma unroll
      for (int f = 0; f < 2; ++f) af[f] = *(const short8*)&As[wr + f * 16 + fr][ksub * 32 + ks];
#pragma unroll
      for (int f = 0; f < 4; ++f) bf[f] = *(const short8*)&Bs[f * 16 + fr][ksub * 32 + ks];
#pragma unroll
      for (int fi = 0; fi < 2; ++fi)
#pragma unroll
        for (int fj = 0; fj < 4; ++fj)
          acc[fi][fj] = __builtin_amdgcn_mfma_f32_16x16x32_bf16(af[fi], bf[fj], acc[fi][fj], 0, 0, 0);
    }
  }

  // epilogue: leaky + bf16 store + per-channel partial sums
  int orow = (lane >> 4) * 4;
  int ocol = lane & 15;
  float s4[4] = {0.f, 0.f, 0.f, 0.f}, ss4[4] = {0.f, 0.f, 0.f, 0.f};
#pragma unroll
  for (int fi = 0; fi < 2; ++fi)
#pragma unroll
    for (int rr = 0; rr < 4; ++rr) {
      int rowg = bi + wr + fi * 16 + orow + rr;
      size_t base = ((size_t)b * N_ + rowg) * D_ + bj;
#pragma unroll
      for (int fj = 0; fj < 4; ++fj) {
        float v = acc[fi][fj][rr];
        v = (v >= 0.f) ? v : LEAKY * v;
        pre[base + fj * 16 + ocol] = f2bf(v);
        s4[fj] += v;
        ss4[fj] = fmaf(v, v, ss4[fj]);
      }
    }
#pragma unroll
  for (int fj = 0; fj < 4; ++fj) {
    s4[fj] += __shfl_xor(s4[fj], 16);  s4[fj] += __shfl_xor(s4[fj], 32);
    ss4[fj] += __shfl_xor(ss4[fj], 16); ss4[fj] += __shfl_xor(ss4[fj], 32);
  }
  __syncthreads();
  float* sred = (float*)As;               // reuse LDS
  if (lane < 16) {
#pragma unroll
    for (int fj = 0; fj < 4; ++fj) {
      sred[(wid * 4 + fj) * 16 + lane] = s4[fj];
      sred[256 + (wid * 4 + fj) * 16 + lane] = ss4[fj];
    }
  }
  __syncthreads();
  if (t < 64) {
    float s = 0.f, ss = 0.f;
#pragma unroll
    for (int w4 = 0; w4 < 4; ++w4) {
      s  += sred[(w4 * 4 + (t >> 4)) * 16 + (t & 15)];
      ss += sred[256 + (w4 * 4 + (t >> 4)) * 16 + (t & 15)];
    }
    ps[(size_t)lin * 64 + t] = s;
    pss[(size_t)lin * 64 + t] = ss;
  }
}

// ---------- BN finalize: reduce 512-block partials -> scale/shift per channel
__global__ void k_final(const float* __restrict__ ps, const float* __restrict__ pss,
                        const float* __restrict__ bnw, const float* __restrict__ bnb,
                        float* __restrict__ scale, float* __restrict__ shift) {
  int t = threadIdx.x;  // 256 channels
  int bxi = t >> 6, col = t & 63;
  float s = 0.f, ss = 0.f;
  for (int byi = 0; byi < 16; ++byi)
    for (int bb = 0; bb < 8; ++bb) {
      int lin = (byi * 4 + bxi) * 8 + bb;
      s += ps[(size_t)lin * 64 + col];
      ss += pss[(size_t)lin * 64 + col];
    }
  const float invN = 1.0f / (B_ * N_);
  float mean = s * invN;
  float var = fmaf(-mean, mean, ss * invN);
  float istd = rsqrtf(var + EPS);
  float sc = istd * bnw[t];
  scale[t] = sc;
  shift[t] = fmaf(-mean, sc, bnb[t]);
}

// ---------- normalize + transpose (b,n,d) bf16 -> (b,d,n) f32
__global__ __launch_bounds__(256) void k_out(const unsigned short* __restrict__ pre,
                                             const float* __restrict__ scale,
                                             const float* __restrict__ shift,
                                             float* __restrict__ out) {
  __shared__ float tile[32][33];
  int blk = blockIdx.x;
  int d0 = (blk % (D_ / 32)) * 32;
  int n0 = ((blk / (D_ / 32)) % (N_ / 32)) * 32;
  int b = blk / ((D_ / 32) * (N_ / 32));
  int tc = threadIdx.x & 31;
  int tr = threadIdx.x >> 5;
  const unsigned short* pb = pre + ((size_t)b * N_ + n0) * D_ + d0;
#pragma unroll
  for (int i = 0; i < 4; ++i) {
    int r = tr + i * 8;
    tile[r][tc] = bf2f(pb[(size_t)r * D_ + tc]);
  }
  __syncthreads();
  float* ob = out + ((size_t)b * D_ + d0) * N_ + n0;
#pragma unroll
  for (int i = 0; i < 4; ++i) {
    int r = tr + i * 8;
    float vv = tile[tc][r];
    ob[(size_t)r * N_ + tc] = fmaf(vv, scale[d0 + r], shift[d0 + r]);
  }
}

extern "C" void kernel_launch(void* const* d_in, const int* in_sizes, int n_in,
                              void* d_out, int out_size, void* d_ws, size_t ws_size,
                              hipStream_t stream) {
  const float* x = (const float*)d_in[0];
  const float* W = (const float*)d_in[1];
  const float* bnw = (const float*)d_in[2];
  const float* bnb = (const float*)d_in[3];
  float* out = (float*)d_out;

  char* w = (char*)d_ws;
  short* xt = (short*)w;            w += (size_t)B_ * N_ * C_ * 2;     // (b,n,c) bf16
  short* wt = (short*)w;            w += (size_t)D_ * C_ * 2;          // (d,c) bf16
  short* supT = (short*)w;          w += (size_t)B_ * D_ * N_ * 2;     // (b,d,m) bf16
  short* S = (short*)w;             w += (size_t)B_ * N_ * N_ * 2;     // (b,n,m) bf16
  unsigned short* pre = (unsigned short*)w; w += (size_t)B_ * N_ * D_ * 2; // (b,n,d) bf16
  float* ps = (float*)w;            w += (size_t)512 * 64 * 4;         // stat partials
  float* pss = (float*)w;           w += (size_t)512 * 64 * 4;
  float* scale = (float*)w;         w += D_ * 4;
  float* shift = (float*)w;         w += D_ * 4;

  // 1. layout prep
  k_transpose_cast<<<dim3(N_ / 32, C_ / 32, B_), 256, 0, stream>>>(
      x, (unsigned short*)xt, C_, N_, (size_t)C_ * N_, (size_t)N_ * C_);
  k_transpose_cast<<<dim3(D_ / 32, C_ / 32, 1), 256, 0, stream>>>(
      W, (unsigned short*)wt, C_, D_, 0, 0);

  // 2. supT(d,m) = wt . xt^T
  k_gemm<C_, 64, false><<<dim3(N_ / 64, 2, B_), 256, 0, stream>>>(
      wt, xt, (unsigned short*)supT, 0, (size_t)N_ * C_, (size_t)D_ * N_, N_, 0);

  // 3. S(n,m) = xt . xt^T  — batch->XCD pinned
  k_gemm<C_, 128, true><<<dim3(16 * 16 * B_, 1, 1), 256, 0, stream>>>(
      xt, xt, (unsigned short*)S, (size_t)N_ * C_, (size_t)N_ * C_, (size_t)N_ * N_, N_, 16);

  // 4. softmax + topk mask (in place), one wave per row
  k_softmax_topk<<<B_ * N_ / 4, 256, 0, stream>>>((unsigned short*)S);

  // 5. PV (BK=64), leaky + bf16 out + fused BN partials — batch->XCD pinned
  k_pv<<<dim3(4 * 16 * B_, 1, 1), 256, 0, stream>>>(S, supT, pre, ps, pss);

  // 6. finalize BN + output
  k_final<<<1, 256, 0, stream>>>(ps, pss, bnw, bnb, scale, shift);
  k_out<<<B_ * (N_ / 32) * (D_ / 32), 256, 0, stream>>>(pre, scale, shift, out);
}

// Round 9
// 108.390 us; speedup vs baseline: 1.5914x; 1.1137x over previous
//
#include <hip/hip_runtime.h>

#define B_ 8
#define C_ 256
#define N_ 2048
#define D_ 256
#define KKEEP 1843      // round(2048 * 0.9)
#define LEAKY 0.01f
#define EPS 1e-5f

using short8  = __attribute__((ext_vector_type(8))) short;
using ushort8 = __attribute__((ext_vector_type(8))) unsigned short;
using ushort4v = __attribute__((ext_vector_type(4))) unsigned short;
using f32x4   = __attribute__((ext_vector_type(4))) float;

__device__ inline unsigned short f2bf(float x) {          // RNE f32->bf16
  unsigned u = __float_as_uint(x);
  u += 0x7fffu + ((u >> 16) & 1u);
  return (unsigned short)(u >> 16);
}
__device__ inline float bf2f(unsigned short u) { return __uint_as_float(((unsigned)u) << 16); }

// async global -> LDS, 16B per lane. LDS dest is wave-uniform base + lane*16.
__device__ inline void gload16(const void* g, void* l) {
  __builtin_amdgcn_global_load_lds(
      (const __attribute__((address_space(1))) void*)g,
      (__attribute__((address_space(3))) void*)l, 16, 0, 0);
}

// ---------- transpose + cast: src (rows x cols) fp32 -> dst (cols x rows) bf16
__global__ __launch_bounds__(256) void k_transpose_cast(const float* __restrict__ src,
                                                        unsigned short* __restrict__ dst,
                                                        int rows, int cols,
                                                        size_t srcBatch, size_t dstBatch) {
  __shared__ float tile[32][33];
  int b = blockIdx.z;
  src += (size_t)b * srcBatch;
  dst += (size_t)b * dstBatch;
  int i0 = blockIdx.y * 32;   // src row (c)
  int j0 = blockIdx.x * 32;   // src col (n)
  int t = threadIdx.x;
  int tc = t & 31, tr = t >> 5;
#pragma unroll
  for (int k = 0; k < 4; ++k)
    tile[tr + k * 8][tc] = src[(size_t)(i0 + tr + k * 8) * cols + j0 + tc];
  __syncthreads();
  int r2 = t >> 3, q = t & 7;                 // write row j0+r2, 4 consecutive c
  ushort4v v;
#pragma unroll
  for (int l = 0; l < 4; ++l) v[l] = f2bf(tile[q * 4 + l][r2]);
  *(ushort4v*)&dst[(size_t)(j0 + r2) * rows + i0 + q * 4] = v;
}

// ---------- NT MFMA GEMM (support + gram): C[i][j] = sum_k A[i][k]*Bt[j][k]
// 128x128 tile, BK=64, global_load_lds staging (linear LDS), XOR-swizzled
// source + read (T2, both-sides). batch->XCD pinned 1-D grid.
template<int K_, int NX>
__global__ __launch_bounds__(256) void k_gemm(const short* __restrict__ A,
                                              const short* __restrict__ Bt,
                                              unsigned short* __restrict__ Cout,
                                              size_t aStride, size_t bStride, size_t cStride,
                                              int ldc) {
  __shared__ short As[128][64];   // linear; swizzle handled in addresses
  __shared__ short Bs[128][64];
  int lin = blockIdx.x;
  int b = lin & 7;                 // XCD id == batch
  int rest = lin >> 3;
  int bxi = rest % NX, byi = rest / NX;
  const short* Ab = A + (size_t)b * aStride;
  const short* Bb = Bt + (size_t)b * bStride;
  int bi = byi * 128, bj = bxi * 128;
  int t = threadIdx.x, lane = t & 63, wid = t >> 6;
  int wr = (wid >> 1) * 64, wc = (wid & 1) * 64;
  int fr = lane & 15;
  int wbase = wid * 512;           // wave-uniform LDS offset (shorts) per issue

  f32x4 acc[4][4];
  f32x4 z = {0.f, 0.f, 0.f, 0.f};
#pragma unroll
  for (int i = 0; i < 4; ++i)
#pragma unroll
    for (int j = 0; j < 4; ++j) acc[i][j] = z;

  for (int c0 = 0; c0 < K_; c0 += 64) {
    if (c0) __syncthreads();       // previous compute done before overwrite
#pragma unroll
    for (int i = 0; i < 4; ++i) {
      int li = i * 256 + t;
      int row = li >> 3, ch = li & 7;
      int sw = ((ch ^ (row & 7)) << 3);          // pre-swizzled source chunk
      gload16(Ab + (size_t)(bi + row) * K_ + c0 + sw, (short*)As + i * 2048 + wbase);
      gload16(Bb + (size_t)(bj + row) * K_ + c0 + sw, (short*)Bs + i * 2048 + wbase);
    }
    __syncthreads();               // vmcnt(0) drain + barrier
#pragma unroll
    for (int ksub = 0; ksub < 2; ++ksub) {
      int cA = ksub * 4 + (lane >> 4);           // logical 16B chunk 0..7
      short8 af[4], bf[4];
#pragma unroll
      for (int f = 0; f < 4; ++f) {
        int R = wr + f * 16 + fr;
        af[f] = *(const short8*)&As[R][(cA ^ (R & 7)) << 3];
        int Rb = wc + f * 16 + fr;
        bf[f] = *(const short8*)&Bs[Rb][(cA ^ (Rb & 7)) << 3];
      }
#pragma unroll
      for (int fi = 0; fi < 4; ++fi)
#pragma unroll
        for (int fj = 0; fj < 4; ++fj)
          acc[fi][fj] = __builtin_amdgcn_mfma_f32_16x16x32_bf16(af[fi], bf[fj], acc[fi][fj], 0, 0, 0);
    }
  }

  // epilogue: C/D layout: col = lane&15, row = (lane>>4)*4 + reg
  int orow = (lane >> 4) * 4;
  int ocol = lane & 15;
#pragma unroll
  for (int fi = 0; fi < 4; ++fi)
#pragma unroll
    for (int fj = 0; fj < 4; ++fj)
#pragma unroll
      for (int r = 0; r < 4; ++r) {
        size_t idx = (size_t)b * cStride +
                     (size_t)(bi + wr + fi * 16 + orow + r) * ldc +
                     (size_t)(bj + wc + fj * 16 + ocol);
        Cout[idx] = f2bf(acc[fi][fj][r]);
      }
}

// ---------- softmax + exact(bf16-granularity) top-k threshold + mask, one WAVE per row
__global__ __launch_bounds__(256) void k_softmax_topk(unsigned short* __restrict__ S) {
  int t = threadIdx.x;
  int lane = t & 63, wv = t >> 6;
  size_t row = (size_t)blockIdx.x * 4 + wv;
  unsigned short* sr = S + row * N_;

  float e[32];
#pragma unroll
  for (int i = 0; i < 4; ++i) {
    ushort8 raw = *(const ushort8*)(sr + ((size_t)(i * 64 + lane)) * 8);
#pragma unroll
    for (int j = 0; j < 8; ++j) e[i * 8 + j] = bf2f(raw[j]);
  }

  float lm = e[0];
#pragma unroll
  for (int j = 1; j < 32; ++j) lm = fmaxf(lm, e[j]);
#pragma unroll
  for (int m = 1; m <= 16; m <<= 1) lm = fmaxf(lm, __shfl_xor(lm, m));
  lm = fmaxf(__shfl(lm, 0), __shfl(lm, 32));

  float ls = 0.f;
#pragma unroll
  for (int j = 0; j < 32; ++j) { e[j] = __expf(e[j] - lm); ls += e[j]; }
#pragma unroll
  for (int m = 1; m <= 16; m <<= 1) ls += __shfl_xor(ls, m);
  ls = __shfl(ls, 0) + __shfl(ls, 32);
  float inv = 1.0f / ls;

  unsigned kp[16], vo[16];
#pragma unroll
  for (int q = 0; q < 16; ++q)
    kp[q] = (unsigned)f2bf(e[q]) | ((unsigned)f2bf(e[q + 16]) << 16);
#pragma unroll
  for (int q = 0; q < 16; ++q)
    vo[q] = (unsigned)f2bf(e[2 * q] * inv) | ((unsigned)f2bf(e[2 * q + 1] * inv) << 16);

  unsigned tp[16];
#pragma unroll
  for (int q = 0; q < 16; ++q) tp[q] = kp[q];
#pragma unroll
  for (int sI = 0; sI < 4; ++sI) {
    const int s = 8 >> sI;
    const unsigned msk = (s == 8) ? 0x00FF00FFu : (s == 4) ? 0x0F0F0F0Fu
                       : (s == 2) ? 0x33333333u : 0x55555555u;
#pragma unroll
    for (int k = 0; k < 16; ++k) {
      if ((k & s) == 0) {
        unsigned tt = ((tp[k] >> s) ^ tp[k + s]) & msk;
        tp[k + s] ^= tt;
        tp[k]     ^= tt << s;
      }
    }
  }

  unsigned alive = 0xFFFFFFFFu, prefix = 0u;
  int need = KKEEP;
#pragma unroll
  for (int b = 12; b >= 0; b -= 2) {
    unsigned p1 = tp[b + 1], p0 = tp[b];
    unsigned hi = alive & p1;
    unsigned m3 = hi & p0, m2 = hi & ~p0, m1v = (alive & ~p1) & p0;
    unsigned packed = (unsigned)__popc(m3) | ((unsigned)__popc(m2) << 11) |
                      ((unsigned)__popc(m1v) << 22);
#pragma unroll
    for (int m = 1; m <= 16; m <<= 1) packed += __shfl_xor(packed, m);
    unsigned v0 = __shfl(packed, 0), v32 = __shfl(packed, 32);
    int C3 = (int)((v0 & 0x7FFu) + (v32 & 0x7FFu));
    int C2 = (int)(((v0 >> 11) & 0x7FFu) + ((v32 >> 11) & 0x7FFu));
    int C1 = (int)(((v0 >> 22) & 0x7FFu) + ((v32 >> 22) & 0x7FFu));
    int cum2 = C3 + C2, cum1 = cum2 + C1;
    if (C3 >= need)        { alive = m3;  prefix |= 3u << b; }
    else if (cum2 >= need) { alive = m2;  prefix |= 2u << b; need -= C3; }
    else if (cum1 >= need) { alive = m1v; prefix |= 1u << b; need -= cum2; }
    else                   { alive ^= (m3 | m2 | m1v);       need -= cum1; }
  }

#pragma unroll
  for (int i = 0; i < 4; ++i) {
    ushort8 o;
#pragma unroll
    for (int j = 0; j < 8; ++j) {
      int idx = i * 8 + j;
      unsigned key = (kp[idx & 15] >> ((idx >> 4) * 16)) & 0xFFFFu;
      unsigned val = (vo[idx >> 1] >> ((idx & 1) * 16)) & 0xFFFFu;
      o[j] = (key >= prefix) ? (unsigned short)val : (unsigned short)0;
    }
    *(ushort8*)(sr + ((size_t)(i * 64 + lane)) * 8) = o;
  }
}

// ---------- PV GEMM: pre(n,d) = P . supT^T, 128x64 tile, BK=64,
// global_load_lds staging + XOR swizzle; leaky + bf16 out + fused BN partials.
__global__ __launch_bounds__(256) void k_pv(const short* __restrict__ A,   // masked P bf16
                                            const short* __restrict__ Bt,  // supT
                                            unsigned short* __restrict__ pre,
                                            float* __restrict__ ps, float* __restrict__ pss) {
  __shared__ short As[128][64];
  __shared__ short Bs[64][64];
  int lin = blockIdx.x;
  int b = lin & 7;                 // batch -> XCD
  int rest = lin >> 3;
  int bxi = rest & 3;              // nx = 4
  int byi = rest >> 2;
  const short* Ab = A + (size_t)b * N_ * N_;
  const short* Bb = Bt + (size_t)b * D_ * N_;
  int bi = byi * 128, bj = bxi * 64;
  int t = threadIdx.x, lane = t & 63, wid = t >> 6;
  int wr = wid * 32;
  int fr = lane & 15;
  int wbase = wid * 512;

  f32x4 acc[2][4];
  f32x4 z = {0.f, 0.f, 0.f, 0.f};
#pragma unroll
  for (int i = 0; i < 2; ++i)
#pragma unroll
    for (int j = 0; j < 4; ++j) acc[i][j] = z;

  for (int c0 = 0; c0 < N_; c0 += 64) {
    if (c0) __syncthreads();
#pragma unroll
    for (int i = 0; i < 4; ++i) {
      int li = i * 256 + t;
      int row = li >> 3, ch = li & 7;
      int sw = ((ch ^ (row & 7)) << 3);
      gload16(Ab + (size_t)(bi + row) * N_ + c0 + sw, (short*)As + i * 2048 + wbase);
      if (i < 2)
        gload16(Bb + (size_t)(bj + row) * N_ + c0 + sw, (short*)Bs + i * 2048 + wbase);
    }
    __syncthreads();
#pragma unroll
    for (int ksub = 0; ksub < 2; ++ksub) {
      int cA = ksub * 4 + (lane >> 4);
      short8 af[2], bf[4];
#pragma unroll
      for (int f = 0; f < 2; ++f) {
        int R = wr + f * 16 + fr;
        af[f] = *(const short8*)&As[R][(cA ^ (R & 7)) << 3];
      }
#pragma unroll
      for (int f = 0; f < 4; ++f) {
        int Rb = f * 16 + fr;
        bf[f] = *(const short8*)&Bs[Rb][(cA ^ (Rb & 7)) << 3];
      }
#pragma unroll
      for (int fi = 0; fi < 2; ++fi)
#pragma unroll
        for (int fj = 0; fj < 4; ++fj)
          acc[fi][fj] = __builtin_amdgcn_mfma_f32_16x16x32_bf16(af[fi], bf[fj], acc[fi][fj], 0, 0, 0);
    }
  }

  // epilogue: leaky + bf16 store + per-channel partial sums
  int orow = (lane >> 4) * 4;
  int ocol = lane & 15;
  float s4[4] = {0.f, 0.f, 0.f, 0.f}, ss4[4] = {0.f, 0.f, 0.f, 0.f};
#pragma unroll
  for (int fi = 0; fi < 2; ++fi)
#pragma unroll
    for (int rr = 0; rr < 4; ++rr) {
      int rowg = bi + wr + fi * 16 + orow + rr;
      size_t base = ((size_t)b * N_ + rowg) * D_ + bj;
#pragma unroll
      for (int fj = 0; fj < 4; ++fj) {
        float v = acc[fi][fj][rr];
        v = (v >= 0.f) ? v : LEAKY * v;
        pre[base + fj * 16 + ocol] = f2bf(v);
        s4[fj] += v;
        ss4[fj] = fmaf(v, v, ss4[fj]);
      }
    }
#pragma unroll
  for (int fj = 0; fj < 4; ++fj) {
    s4[fj] += __shfl_xor(s4[fj], 16);  s4[fj] += __shfl_xor(s4[fj], 32);
    ss4[fj] += __shfl_xor(ss4[fj], 16); ss4[fj] += __shfl_xor(ss4[fj], 32);
  }
  __syncthreads();
  float* sred = (float*)As;               // reuse LDS
  if (lane < 16) {
#pragma unroll
    for (int fj = 0; fj < 4; ++fj) {
      sred[(wid * 4 + fj) * 16 + lane] = s4[fj];
      sred[256 + (wid * 4 + fj) * 16 + lane] = ss4[fj];
    }
  }
  __syncthreads();
  if (t < 64) {
    float s = 0.f, ss = 0.f;
#pragma unroll
    for (int w4 = 0; w4 < 4; ++w4) {
      s  += sred[(w4 * 4 + (t >> 4)) * 16 + (t & 15)];
      ss += sred[256 + (w4 * 4 + (t >> 4)) * 16 + (t & 15)];
    }
    ps[(size_t)lin * 64 + t] = s;
    pss[(size_t)lin * 64 + t] = ss;
  }
}

// ---------- BN finalize: reduce 512-block partials -> scale/shift per channel
__global__ void k_final(const float* __restrict__ ps, const float* __restrict__ pss,
                        const float* __restrict__ bnw, const float* __restrict__ bnb,
                        float* __restrict__ scale, float* __restrict__ shift) {
  int t = threadIdx.x;  // 256 channels
  int bxi = t >> 6, col = t & 63;
  float s = 0.f, ss = 0.f;
  for (int byi = 0; byi < 16; ++byi)
    for (int bb = 0; bb < 8; ++bb) {
      int lin = (byi * 4 + bxi) * 8 + bb;
      s += ps[(size_t)lin * 64 + col];
      ss += pss[(size_t)lin * 64 + col];
    }
  const float invN = 1.0f / (B_ * N_);
  float mean = s * invN;
  float var = fmaf(-mean, mean, ss * invN);
  float istd = rsqrtf(var + EPS);
  float sc = istd * bnw[t];
  scale[t] = sc;
  shift[t] = fmaf(-mean, sc, bnb[t]);
}

// ---------- normalize + transpose (b,n,d) bf16 -> (b,d,n) f32
__global__ __launch_bounds__(256) void k_out(const unsigned short* __restrict__ pre,
                                             const float* __restrict__ scale,
                                             const float* __restrict__ shift,
                                             float* __restrict__ out) {
  __shared__ float tile[32][33];
  int blk = blockIdx.x;
  int d0 = (blk % (D_ / 32)) * 32;
  int n0 = ((blk / (D_ / 32)) % (N_ / 32)) * 32;
  int b = blk / ((D_ / 32) * (N_ / 32));
  int tc = threadIdx.x & 31;
  int tr = threadIdx.x >> 5;
  const unsigned short* pb = pre + ((size_t)b * N_ + n0) * D_ + d0;
#pragma unroll
  for (int i = 0; i < 4; ++i) {
    int r = tr + i * 8;
    tile[r][tc] = bf2f(pb[(size_t)r * D_ + tc]);
  }
  __syncthreads();
  float* ob = out + ((size_t)b * D_ + d0) * N_ + n0;
#pragma unroll
  for (int i = 0; i < 4; ++i) {
    int r = tr + i * 8;
    float vv = tile[tc][r];
    ob[(size_t)r * N_ + tc] = fmaf(vv, scale[d0 + r], shift[d0 + r]);
  }
}

extern "C" void kernel_launch(void* const* d_in, const int* in_sizes, int n_in,
                              void* d_out, int out_size, void* d_ws, size_t ws_size,
                              hipStream_t stream) {
  const float* x = (const float*)d_in[0];
  const float* W = (const float*)d_in[1];
  const float* bnw = (const float*)d_in[2];
  const float* bnb = (const float*)d_in[3];
  float* out = (float*)d_out;

  char* w = (char*)d_ws;
  short* xt = (short*)w;            w += (size_t)B_ * N_ * C_ * 2;     // (b,n,c) bf16
  short* wt = (short*)w;            w += (size_t)D_ * C_ * 2;          // (d,c) bf16
  short* supT = (short*)w;          w += (size_t)B_ * D_ * N_ * 2;     // (b,d,m) bf16
  short* S = (short*)w;             w += (size_t)B_ * N_ * N_ * 2;     // (b,n,m) bf16
  unsigned short* pre = (unsigned short*)w; w += (size_t)B_ * N_ * D_ * 2; // (b,n,d) bf16
  float* ps = (float*)w;            w += (size_t)512 * 64 * 4;         // stat partials
  float* pss = (float*)w;           w += (size_t)512 * 64 * 4;
  float* scale = (float*)w;         w += D_ * 4;
  float* shift = (float*)w;         w += D_ * 4;

  // 1. layout prep
  k_transpose_cast<<<dim3(N_ / 32, C_ / 32, B_), 256, 0, stream>>>(
      x, (unsigned short*)xt, C_, N_, (size_t)C_ * N_, (size_t)N_ * C_);
  k_transpose_cast<<<dim3(D_ / 32, C_ / 32, 1), 256, 0, stream>>>(
      W, (unsigned short*)wt, C_, D_, 0, 0);

  // 2. supT(d,m) = wt . xt^T  (M=256, cols=2048) — 256 blocks, batch->XCD pinned
  k_gemm<C_, 16><<<dim3(8 * 16 * 2, 1, 1), 256, 0, stream>>>(
      wt, xt, (unsigned short*)supT, 0, (size_t)N_ * C_, (size_t)D_ * N_, N_);

  // 3. S(n,m) = xt . xt^T — 2048 blocks, batch->XCD pinned
  k_gemm<C_, 16><<<dim3(8 * 16 * 16, 1, 1), 256, 0, stream>>>(
      xt, xt, (unsigned short*)S, (size_t)N_ * C_, (size_t)N_ * C_, (size_t)N_ * N_, N_);

  // 4. softmax + topk mask (in place), one wave per row
  k_softmax_topk<<<B_ * N_ / 4, 256, 0, stream>>>((unsigned short*)S);

  // 5. PV (BK=64, gload_lds), leaky + bf16 out + fused BN partials
  k_pv<<<dim3(4 * 16 * 8, 1, 1), 256, 0, stream>>>(S, supT, pre, ps, pss);

  // 6. finalize BN + output
  k_final<<<1, 256, 0, stream>>>(ps, pss, bnw, bnb, scale, shift);
  k_out<<<B_ * (N_ / 32) * (D_ / 32), 256, 0, stream>>>(pre, scale, shift, out);
}